// Round 1
// baseline (142.171 us; speedup 1.0000x reference)
//
#include <hip/hip_runtime.h>
#include <hip/hip_bf16.h>

// MultiHeadAttention_66340064854505 — MI355X/gfx950
// B=1, N=4096, E=512, H=8, dk=64, WS=128, NDIM=16. All I/O fp32; MFMA in bf16.
//
// R9: fused QKV-GEMM + attention. Attention is fully block-local per (window,head),
// so each of 256 blocks (512 thr, 8 waves) computes its own Q,K,V = x[128 rows] @
// W[192 cols] (K=512, BK=32, dbuf LDS, 1 barrier/K-step) into LDS, then QK^T ->
// exp/mask -> PV in-block. Removes the 25 MB qkv global round trip + one device sync.
// vtot moved off the critical path: out@Wo = (SV/den)@Wo + sum_h rd[row,h]*vtWoH[h,:],
// rd = 1/denom (fp32, written by fused kernel), vtWoH[h] = vt_h @ W_out (fp32, computed
// by 8 spare blocks in the passC dispatch from xpart — no dependency on the fused kernel).
// CEMA group scan flattened: passB = single 128-chunk scan -> global chunk inits (hin);
// passC simplified (no T/B2 machinery).
// Dispatches: D1(prep||passA) -> D2(fusedQKVattn||passB) -> D3(passC||vtWoH) -> D4(outGEMM).

typedef __bf16 bf16x8 __attribute__((ext_vector_type(8)));
typedef float  f32x4  __attribute__((ext_vector_type(4)));

#define N_TOK   4096
#define EDIM    512
#define DKH     64
#define WSZ     128
#define CCH     128   // CEMA chunks
#define CLEN    32    // CEMA chunk length

__device__ __forceinline__ void glds16(const void* gsrc, void* ldst) {
  __builtin_amdgcn_global_load_lds(
      (const __attribute__((address_space(1))) void*)gsrc,
      (__attribute__((address_space(3))) void*)ldst,
      16, 0, 0);
}

// ================= D1: weight prep (blocks 0..255) || CEMA passA (blocks 256..511) =================
// UNCHANGED from R8 (proven).
__global__ __launch_bounds__(256) void fused_prep_cemaA(const float* __restrict__ Wq,
                                                        __bf16* __restrict__ WtQ,
                                                        const float* __restrict__ Wo,
                                                        __bf16* __restrict__ WtO,
                                                        const float* __restrict__ x,
                                                        const float* __restrict__ pc,
                                                        const float* __restrict__ qc,
                                                        float* __restrict__ h_end,
                                                        __bf16* __restrict__ x_bf,
                                                        float* __restrict__ xpart) {
  const int b = blockIdx.x, t = threadIdx.x;
  if (b < 256) {
    __shared__ float tile[64][65];
    int bx = b & 31;
    const int by = b >> 5;
    const float* in;
    __bf16* out;
    int C;
    if (bx < 24) { in = Wq; out = WtQ; C = 1536; }
    else         { bx -= 24; in = Wo; out = WtO; C = 512; }
    const int R = 512;
#pragma unroll
    for (int i = 0; i < 16; i++) {
      int idx = t + i * 256;
      int r = idx >> 6, c = idx & 63;
      tile[r][c] = in[(size_t)(by * 64 + r) * C + bx * 64 + c];
    }
    __syncthreads();
#pragma unroll
    for (int i = 0; i < 16; i++) {
      int idx = t + i * 256;
      int r = idx >> 6, c = idx & 63;
      out[(size_t)(bx * 64 + r) * R + by * 64 + c] = (__bf16)tile[c][r];
    }
  } else {
    const int bb = b - 256;
    const int c = bb >> 1;
    const int e = ((bb & 1) << 8) + t;
    float p[16], q[16], h[16];
#pragma unroll
    for (int d4 = 0; d4 < 4; d4++) {
      const float4 pv = ((const float4*)(pc + e * 16))[d4];
      const float4 qv = ((const float4*)(qc + e * 16))[d4];
      p[d4 * 4 + 0] = pv.x; p[d4 * 4 + 1] = pv.y; p[d4 * 4 + 2] = pv.z; p[d4 * 4 + 3] = pv.w;
      q[d4 * 4 + 0] = qv.x; q[d4 * 4 + 1] = qv.y; q[d4 * 4 + 2] = qv.z; q[d4 * 4 + 3] = qv.w;
    }
#pragma unroll
    for (int d = 0; d < 16; d++) h[d] = 0.f;
    const float* xp = x + (size_t)c * CLEN * EDIM + e;
    __bf16* xb = x_bf + (size_t)c * CLEN * EDIM + e;
    float sx = 0.f;
#pragma unroll 4
    for (int tt = 0; tt < CLEN; tt++) {
      const float xv = xp[(size_t)tt * EDIM];
      xb[(size_t)tt * EDIM] = (__bf16)xv;
      sx += xv;
#pragma unroll
      for (int d = 0; d < 16; d++) h[d] = fmaf(p[d], xv, q[d] * h[d]);
    }
    xpart[(size_t)c * 512 + e] = sx;
    float* o = h_end + (size_t)c * 8192 + e * 16;
#pragma unroll
    for (int d = 0; d < 16; d++) o[d] = h[d];
  }
}

// ================= D2: fused QKV+attention (0..255, 512 thr) || CEMA passB flat (256..271) =================
// LDS map (58,880 B):
//   [    0,20480) As0(8K)+Bs0(12K)   \ GEMM dbuf; overlaid after GEMM by
//   [20480,40960) As1(8K)+Bs1(12K)   /   Qs[128][72] @0 (18432) + Ks[128][72] @18432 (18432);
//                                        Ws[128][136] @0 (34816) overlays Qs/Ks after QK^T.
//   [40960,58368) Vt[64][136] (17408)
//   [58368,58880) rowsum[128] f32
// Strides padded (72 / 136 bf16) so ds_read_b128 fragment reads hit the 8-access bank floor.
__global__ __launch_bounds__(512) void fused_qkv_attn_scanB(const __bf16* __restrict__ x_bf,
                                                            const __bf16* __restrict__ WtQ,
                                                            const float* __restrict__ b_qkv,
                                                            const float* __restrict__ qc,
                                                            const float* __restrict__ h_end,
                                                            float* __restrict__ hin,
                                                            __bf16* __restrict__ out_attn,
                                                            float* __restrict__ rd) {
  const int B = blockIdx.x, t = threadIdx.x;
  __shared__ f32x4 smemv[3680];
  if (B >= 256) {
    // passB: global chunk-prefix scan, one channel per thread (16 blocks x 512).
    const int i = (B - 256) * 512 + t;
    const float q = qc[i];
    float Q = q * q; Q = Q * Q; Q = Q * Q; Q = Q * Q; Q = Q * Q;  // q^32
    float L = 0.f;
#pragma unroll 4
    for (int c = 0; c < 128; c++) {
      hin[(size_t)c * 8192 + i] = L;          // hin[c] = global init state for chunk c
      L = h_end[(size_t)c * 8192 + i] + Q * L;
    }
    return;
  }
  char* sb = (char*)smemv;
  const int lane = t & 63, wid = t >> 6;
  const int quad = lane >> 4, c16 = lane & 15;
  // XCD-aware decode: blocks sharing a window (same x_bf slice) land on one XCD.
  const int xcd = B & 7, h = (B >> 3) & 7, wg = B >> 6;
  const int w = wg * 8 + xcd;

  __bf16* AsP[2] = {(__bf16*)sb, (__bf16*)(sb + 20480)};
  __bf16* BsP[2] = {(__bf16*)(sb + 8192), (__bf16*)(sb + 28672)};

  // ---- Phase G: QKV GEMM, C[128 rows][192 cols] = x[w] @ Wqkv[h-slice], K=512 ----
  const int wm = (wid & 3) * 32, wc = (wid >> 2) * 96;
  f32x4 acc[2][6] = {};
  const int ar = t >> 2, ac8 = (t & 3) * 8;
  const __bf16* gA = x_bf + (size_t)(w * 128 + ar) * 512 + ac8;
  const int grB0 = (ar < 64) ? (h * 64 + ar) : (512 + h * 64 + (ar - 64));
  const __bf16* gB0 = WtQ + (size_t)grB0 * 512 + ac8;
  const __bf16* gB1 = WtQ + (size_t)(1024 + h * 64 + ar) * 512 + ac8;  // valid only for wid<4

  glds16(gA, AsP[0] + t * 8);
  glds16(gB0, BsP[0] + t * 8);
  if (wid < 4) glds16(gB1, BsP[0] + 4096 + t * 8);
  __syncthreads();

  int cur = 0;
  for (int k0 = 0; k0 < 512; k0 += 32) {
    if (k0 + 32 < 512) {  // prefetch next K-tile into the other buffer (overlaps MFMA below)
      glds16(gA + k0 + 32, AsP[cur ^ 1] + t * 8);
      glds16(gB0 + k0 + 32, BsP[cur ^ 1] + t * 8);
      if (wid < 4) glds16(gB1 + k0 + 32, BsP[cur ^ 1] + 4096 + t * 8);
    }
    bf16x8 af[2], bfr[6];
#pragma unroll
    for (int i = 0; i < 2; i++)
      af[i] = *(const bf16x8*)&AsP[cur][(wm + i * 16 + c16) * 32 + quad * 8];
#pragma unroll
    for (int j = 0; j < 6; j++)
      bfr[j] = *(const bf16x8*)&BsP[cur][(wc + j * 16 + c16) * 32 + quad * 8];
#pragma unroll
    for (int mi = 0; mi < 2; mi++)
#pragma unroll
      for (int ni = 0; ni < 6; ni++)
        acc[mi][ni] = __builtin_amdgcn_mfma_f32_16x16x32_bf16(af[mi], bfr[ni], acc[mi][ni], 0, 0, 0);
    __syncthreads();  // drains vmcnt(0): next tile staged; all reads of cur done -> safe flip
    cur ^= 1;
  }

  // ---- write Q,K (row-major, pad 72) and V (transposed, pad 136) to LDS, + bias ----
  __bf16* Qs = (__bf16*)sb;            // stride 72
  __bf16* Ks = (__bf16*)(sb + 18432);  // stride 72
  __bf16* Vt = (__bf16*)(sb + 40960);  // stride 136, [d][token]
  __bf16* Ws = (__bf16*)sb;            // stride 136 (valid after QK^T)
  float* rowsum = (float*)(sb + 58368);

#pragma unroll
  for (int ni = 0; ni < 6; ni++) {
    const int cc = wc + ni * 16 + c16;   // [0,192); group uniform per frag (16-aligned)
    const int g = cc >> 6;               // 0=q 1=k 2=v
    const int d = cc & 63;
    const float bv = b_qkv[g * 512 + h * 64 + d];
#pragma unroll
    for (int mi = 0; mi < 2; mi++)
#pragma unroll
      for (int r = 0; r < 4; r++) {
        const int row = wm + mi * 16 + quad * 4 + r;
        const float v = acc[mi][ni][r] + bv;
        if (g == 0)      Qs[row * 72 + d] = (__bf16)v;
        else if (g == 1) Ks[row * 72 + d] = (__bf16)v;
        else             Vt[d * 136 + row] = (__bf16)v;
      }
  }
  __syncthreads();

  // ---- QK^T: S[128][128], 8 waves = 2(row) x 4(col) ----
  const int swm = (wid & 1) * 64, swn = (wid >> 1) * 32;
  f32x4 accs[4][2] = {};
#pragma unroll
  for (int k0 = 0; k0 < DKH; k0 += 32) {
    bf16x8 af2[4], bf2[2];
#pragma unroll
    for (int i = 0; i < 4; i++)
      af2[i] = *(const bf16x8*)&Qs[(swm + i * 16 + c16) * 72 + k0 + quad * 8];
#pragma unroll
    for (int j = 0; j < 2; j++)
      bf2[j] = *(const bf16x8*)&Ks[(swn + j * 16 + c16) * 72 + k0 + quad * 8];
#pragma unroll
    for (int mi = 0; mi < 4; mi++)
#pragma unroll
      for (int ni = 0; ni < 2; ni++)
        accs[mi][ni] = __builtin_amdgcn_mfma_f32_16x16x32_bf16(af2[mi], bf2[ni], accs[mi][ni], 0, 0, 0);
  }
  __syncthreads();            // Qs/Ks reads done -> Ws may overlay
  if (t < 128) rowsum[t] = 0.f;
  __syncthreads();

  // ---- exp/mask -> Ws (bf16), rowsum partials ----
#pragma unroll
  for (int mi = 0; mi < 4; mi++) {
    float rs[4] = {0.f, 0.f, 0.f, 0.f};
#pragma unroll
    for (int ni = 0; ni < 2; ni++) {
      const int j = swn + ni * 16 + c16;
#pragma unroll
      for (int r = 0; r < 4; r++) {
        const int i = swm + mi * 16 + quad * 4 + r;
        const float s = accs[mi][ni][r] * 0.125f;
        const float wv = (j <= i) ? (__expf(s) - 1.f) : 0.f;
        Ws[i * 136 + j] = (__bf16)wv;
        rs[r] += wv;
      }
    }
#pragma unroll
    for (int m = 1; m < 16; m <<= 1)
#pragma unroll
      for (int r = 0; r < 4; r++) rs[r] += __shfl_xor(rs[r], m);
    if (c16 == 0) {
#pragma unroll
      for (int r = 0; r < 4; r++)
        atomicAdd(&rowsum[swm + mi * 16 + quad * 4 + r], rs[r]);
    }
  }
  __syncthreads();

  // ---- PV: O[128][64] = Ws @ V, 8 waves = 4(row) x 2(col) ----
  const int pwm = (wid & 3) * 32, pwn = (wid >> 2) * 32;
  f32x4 acco[2][2] = {};
#pragma unroll
  for (int j0 = 0; j0 < 128; j0 += 32) {
    bf16x8 af3[2], bf3[2];
#pragma unroll
    for (int mi = 0; mi < 2; mi++)
      af3[mi] = *(const bf16x8*)&Ws[(pwm + mi * 16 + c16) * 136 + j0 + quad * 8];
#pragma unroll
    for (int ni = 0; ni < 2; ni++)
      bf3[ni] = *(const bf16x8*)&Vt[(pwn + ni * 16 + c16) * 136 + j0 + quad * 8];
#pragma unroll
    for (int mi = 0; mi < 2; mi++)
#pragma unroll
      for (int ni = 0; ni < 2; ni++)
        acco[mi][ni] = __builtin_amdgcn_mfma_f32_16x16x32_bf16(af3[mi], bf3[ni], acco[mi][ni], 0, 0, 0);
  }

  // ---- epilogue: out_attn = (SV)/denom (vt-term deferred to D4 via rd/vtWoH) ----
#pragma unroll
  for (int mi = 0; mi < 2; mi++)
#pragma unroll
    for (int ni = 0; ni < 2; ni++) {
      const int d = pwn + ni * 16 + c16;
#pragma unroll
      for (int r = 0; r < 4; r++) {
        const int i = pwm + mi * 16 + quad * 4 + r;
        const float denom = rowsum[i] + (float)N_TOK;
        out_attn[(size_t)(w * 128 + i) * EDIM + h * 64 + d] = (__bf16)(acco[mi][ni][r] / denom);
      }
    }
  if ((wid >> 2) == 0 && c16 == 0) {
#pragma unroll
    for (int mi = 0; mi < 2; mi++)
#pragma unroll
      for (int r = 0; r < 4; r++) {
        const int i = pwm + mi * 16 + quad * 4 + r;
        rd[(size_t)(w * 128 + i) * 8 + h] = 1.f / (rowsum[i] + (float)N_TOK);
      }
  }
}

// ================= D3: CEMA passC (0..255) || vtWoH (256..263) =================
__global__ __launch_bounds__(256) void fused_cemaC_vtW(const float* __restrict__ x,
                                                       const float* __restrict__ pc,
                                                       const float* __restrict__ qc,
                                                       const float* __restrict__ gma,
                                                       const float* __restrict__ hin,
                                                       float* __restrict__ y,
                                                       const float* __restrict__ xpart,
                                                       const __bf16* __restrict__ WtQ,
                                                       const float* __restrict__ b_qkv,
                                                       const float* __restrict__ W_out,
                                                       float* __restrict__ vtWoH) {
  const int b = blockIdx.x, t = threadIdx.x;
  __shared__ float xsL[512];
  __shared__ float vtL[64];
  if (b < 256) {
    // passC: chunk-local recompute from global init hin[c] (B2 machinery gone).
    const int c = b >> 1;
    const int e = ((b & 1) << 8) + t;
    float p[16], q[16], gm[16], hreg[16];
#pragma unroll
    for (int d4 = 0; d4 < 4; d4++) {
      const float4 pv = ((const float4*)(pc + e * 16))[d4];
      const float4 qv = ((const float4*)(qc + e * 16))[d4];
      const float4 gv = ((const float4*)(gma + e * 16))[d4];
      p[d4 * 4 + 0] = pv.x; p[d4 * 4 + 1] = pv.y; p[d4 * 4 + 2] = pv.z; p[d4 * 4 + 3] = pv.w;
      q[d4 * 4 + 0] = qv.x; q[d4 * 4 + 1] = qv.y; q[d4 * 4 + 2] = qv.z; q[d4 * 4 + 3] = qv.w;
      gm[d4 * 4 + 0] = gv.x; gm[d4 * 4 + 1] = gv.y; gm[d4 * 4 + 2] = gv.z; gm[d4 * 4 + 3] = gv.w;
    }
    const float* hi = hin + (size_t)c * 8192 + e * 16;
#pragma unroll
    for (int d = 0; d < 16; d++) hreg[d] = hi[d];
    const float* xp = x + (size_t)c * CLEN * EDIM + e;
    float* yp = y + (size_t)c * CLEN * EDIM + e;
#pragma unroll 4
    for (int tt = 0; tt < CLEN; tt++) {
      const float xv = xp[(size_t)tt * EDIM];
      float acc = 0.f;
#pragma unroll
      for (int d = 0; d < 16; d++) {
        hreg[d] = fmaf(p[d], xv, q[d] * hreg[d]);
        acc = fmaf(gm[d], hreg[d], acc);
      }
      yp[(size_t)tt * EDIM] = acc;
    }
  } else {
    // vtWoH[h][:] = (xsum @ Wv_h + N*b_v_h) @ Wo_h  (all fp32; one block per head)
    const int h = b - 256;
    float s0 = 0.f, s1 = 0.f;
    for (int c = 0; c < CCH; c++) {
      s0 += xpart[(size_t)c * 512 + t];
      s1 += xpart[(size_t)c * 512 + 256 + t];
    }
    xsL[t] = s0; xsL[256 + t] = s1;
    __syncthreads();
    const int wid = t >> 6, lane = t & 63;
#pragma unroll
    for (int u = 0; u < 16; u++) {
      const int c = wid * 16 + u;  // [0,64)
      const bf16x8 wv = *(const bf16x8*)(WtQ + (size_t)(1024 + h * 64 + c) * 512 + lane * 8);
      float s = 0.f;
#pragma unroll
      for (int z = 0; z < 8; z++) s = fmaf((float)wv[z], xsL[lane * 8 + z], s);
#pragma unroll
      for (int m = 1; m < 64; m <<= 1) s += __shfl_xor(s, m);
      if (lane == 0) vtL[c] = s + (float)N_TOK * b_qkv[1024 + h * 64 + c];
    }
    __syncthreads();
#pragma unroll
    for (int oo = 0; oo < 2; oo++) {
      const int o = oo * 256 + t;
      float accv = 0.f;
#pragma unroll 8
      for (int d = 0; d < 64; d++)
        accv = fmaf(vtL[d], W_out[(size_t)(h * 64 + d) * 512 + o], accv);
      vtWoH[(size_t)h * 512 + o] = accv;
    }
  }
}

// ================= D4: out-projection GEMM + fp32 vt fix-up + adaptive mix =================
__global__ __launch_bounds__(256) void gemm_out_kernel(const __bf16* __restrict__ A,
                                                       const __bf16* __restrict__ Bt,
                                                       const float* __restrict__ bias,
                                                       float* __restrict__ Cf,
                                                       const float* __restrict__ cema,
                                                       const float* __restrict__ aw,
                                                       const float* __restrict__ rd,
                                                       const float* __restrict__ vtWoH) {
  __shared__ __bf16 AsB[2][64 * 32];
  __shared__ __bf16 BsB[2][64 * 32];
  const int t = threadIdx.x;
  const int lane = t & 63, wid = t >> 6;
  const int quad = lane >> 4, c16 = lane & 15;
  const int wm = (wid & 1) * 32, wn = (wid >> 1) * 32;
  const int m0 = blockIdx.x * 64, n0 = blockIdx.y * 64;
  f32x4 acc[2][2] = {};
  const int ar = t >> 2, ac8 = (t & 3) * 8;
  const __bf16* gA = A + (size_t)(m0 + ar) * EDIM + ac8;
  const __bf16* gB = Bt + (size_t)(n0 + ar) * EDIM + ac8;

  glds16(gA, AsB[0] + t * 8);
  glds16(gB, BsB[0] + t * 8);
  __syncthreads();
  int cur = 0;
  for (int k0 = 0; k0 < EDIM; k0 += 32) {
    if (k0 + 32 < EDIM) {
      glds16(gA + k0 + 32, AsB[cur ^ 1] + t * 8);
      glds16(gB + k0 + 32, BsB[cur ^ 1] + t * 8);
    }
    bf16x8 af[2], bfr[2];
#pragma unroll
    for (int i = 0; i < 2; i++) {
      af[i] = *(const bf16x8*)&AsB[cur][(wm + i * 16 + c16) * 32 + quad * 8];
      bfr[i] = *(const bf16x8*)&BsB[cur][(wn + i * 16 + c16) * 32 + quad * 8];
    }
#pragma unroll
    for (int mi = 0; mi < 2; mi++)
#pragma unroll
      for (int ni = 0; ni < 2; ni++)
        acc[mi][ni] = __builtin_amdgcn_mfma_f32_16x16x32_bf16(af[mi], bfr[ni], acc[mi][ni], 0, 0, 0);
    __syncthreads();
    cur ^= 1;
  }

  const float a0 = aw[0], a1 = aw[1];
  const float mx = fmaxf(a0, a1);
  const float e0 = __expf(a0 - mx), e1 = __expf(a1 - mx);
  const float w0 = e0 / (e0 + e1);
  const float w1 = 1.f - w0;

  float vw[2][8];
#pragma unroll
  for (int ni = 0; ni < 2; ni++) {
    const int col = n0 + wn + ni * 16 + c16;
#pragma unroll
    for (int hh = 0; hh < 8; hh++) vw[ni][hh] = vtWoH[(size_t)hh * 512 + col];
  }
#pragma unroll
  for (int mi = 0; mi < 2; mi++) {
#pragma unroll
    for (int r = 0; r < 4; r++) {
      const int row = m0 + wm + mi * 16 + quad * 4 + r;
      const float4 rp0 = *(const float4*)(rd + (size_t)row * 8);
      const float4 rp1 = *(const float4*)(rd + (size_t)row * 8 + 4);
#pragma unroll
      for (int ni = 0; ni < 2; ni++) {
        const int col = n0 + wn + ni * 16 + c16;
        float v = acc[mi][ni][r] + bias[col];
        v += rp0.x * vw[ni][0] + rp0.y * vw[ni][1] + rp0.z * vw[ni][2] + rp0.w * vw[ni][3]
           + rp1.x * vw[ni][4] + rp1.y * vw[ni][5] + rp1.z * vw[ni][6] + rp1.w * vw[ni][7];
        v = w0 * v + w1 * cema[(size_t)row * EDIM + col];
        Cf[(size_t)row * EDIM + col] = v;
      }
    }
  }
}

// ---------------- launch ----------------
extern "C" void kernel_launch(void* const* d_in, const int* in_sizes, int n_in,
                              void* d_out, int out_size, void* d_ws, size_t ws_size,
                              hipStream_t stream) {
  const float* x       = (const float*)d_in[0];
  const float* W_qkv   = (const float*)d_in[1];
  const float* b_qkv   = (const float*)d_in[2];
  const float* W_out   = (const float*)d_in[3];
  const float* b_out   = (const float*)d_in[4];
  // d_in[5] = omega (unused by reference)
  const float* p_coeff = (const float*)d_in[6];
  const float* q_coeff = (const float*)d_in[7];
  const float* gamma   = (const float*)d_in[8];
  const float* aw      = (const float*)d_in[9];

  char* ws = (char*)d_ws;
  __bf16* WtQ      = (__bf16*)(ws);                  //  1,572,864
  __bf16* WtO      = (__bf16*)(ws + 1572864);        //    524,288
  __bf16* x_bf     = (__bf16*)(ws + 2097152);        //  4,194,304
  float*  h_end    = (float*) (ws + 6291456);        //  4,194,304
  float*  hin      = (float*) (ws + 10485760);       //  4,194,304
  float*  xpart    = (float*) (ws + 14680064);       //    262,144
  __bf16* out_attn = (__bf16*)(ws + 14942208);       //  4,194,304
  float*  rd       = (float*) (ws + 19136512);       //    131,072
  float*  vtWoH    = (float*) (ws + 19267584);       //     16,384
  float*  y        = (float*) (ws + 19283968);       //  8,388,608  (end ~27.7 MB)

  fused_prep_cemaA<<<512, 256, 0, stream>>>(W_qkv, WtQ, W_out, WtO,
                                            x, p_coeff, q_coeff, h_end, x_bf, xpart);

  fused_qkv_attn_scanB<<<272, 512, 0, stream>>>(x_bf, WtQ, b_qkv, q_coeff,
                                                h_end, hin, out_attn, rd);

  fused_cemaC_vtW<<<264, 256, 0, stream>>>(x, p_coeff, q_coeff, gamma, hin, y,
                                           xpart, WtQ, b_qkv, W_out, vtWoH);

  gemm_out_kernel<<<dim3(64, 8), 256, 0, stream>>>(out_attn, WtO, b_out,
                                                   (float*)d_out, y, aw, rd, vtWoH);
}